// Round 5
// baseline (161.886 us; speedup 1.0000x reference)
//
#include <hip/hip_runtime.h>
#include <math.h>
#include <limits.h>
#include <stdint.h>

namespace {
constexpr int G = 16;    // num_graphs
constexpr int N = 2048;  // num_nodes
constexpr int K = 16;    // k_neighs
constexpr int C = 20;    // candidates per side (K + diag exclusion + tie slack)
typedef float floatx4 __attribute__((ext_vector_type(4)));
}

// 2*G blocks, 1 wave each. Block b: g = b>>1, side = b&1 (0 = largest t, 1 = smallest t).
// Register-resident: each lane holds its 32-element stripe; selection-without-removal
// via a lexicographic cursor (pv,pi). Emits indices in exact (value, lower-index) order.
__global__ void topk_kernel(const float* __restrict__ emb_t,
                            int* __restrict__ candidx /* [2*G][C] */) {
    const int g = blockIdx.x >> 1;
    const int side = blockIdx.x & 1;
    const int lane = threadIdx.x;            // 64 = one wave
    const float sgn = side ? -1.f : 1.f;     // negate for min side -> always argmax

    float v[32];
    #pragma unroll
    for (int m = 0; m < 32; ++m) v[m] = sgn * emb_t[g * N + lane + 64 * m];

    float pv = INFINITY; int pi = -1;        // last selected (lexicographic cursor)
    for (int p = 0; p < C; ++p) {
        float bv = -INFINITY; int bi = INT_MAX;
        #pragma unroll
        for (int m = 0; m < 32; ++m) {
            const int idx = lane + 64 * m;
            const float x = v[m];
            // eligible iff strictly after (pv,pi) in (value desc, index asc) order
            const bool elig = (x < pv) || (x == pv && idx > pi);
            if (elig && (x > bv || (x == bv && idx < bi))) { bv = x; bi = idx; }
        }
        #pragma unroll
        for (int off = 32; off >= 1; off >>= 1) {
            const float ov = __shfl_xor(bv, off);
            const int   oi = __shfl_xor(bi, off);
            if (ov > bv || (ov == bv && oi < bi)) { bv = ov; bi = oi; }
        }
        if (lane == 0) candidx[blockIdx.x * C + p] = bi;
        pv = bv; pi = bi;
    }
}

// Per-row selection logic: returns this lane's 32-bit membership word
// (lane l owns columns [32l, 32l+32)). Exact lax.top_k semantics incl. ties.
__device__ __forceinline__ unsigned row_word(const float* __restrict__ emb_s,
                                             const float* __restrict__ emb_t,
                                             const int* __restrict__ candidx,
                                             int row, int lane) {
    const int g = row >> 11;             // N = 2048
    const int i = row & (N - 1);
    const float s = emb_s[row];

    int idx = INT_MAX;
    bool sel = false;
    if (s != 0.0f) {
        const int* list = candidx + (g * 2 + (s < 0.0f)) * C;
        float p = -INFINITY;
        if (lane < C) {
            idx = list[lane];
            p = s * emb_t[g * N + idx];          // same rounding as reference adj
            if (idx == i) { p = -INFINITY; idx = INT_MAX; }  // exclude diagonal
        }
        int rank = 0;
        for (int c = 0; c < C; ++c) {
            const float pc = __shfl(p, c);
            const int   ic = __shfl(idx, c);
            if (pc > p || (pc == p && ic < idx)) ++rank;
        }
        sel = (lane < C) && (rank < K) && (idx != INT_MAX);
    } else {
        // s == +/-0: all products are +/-0 (compare-equal) -> lowest K indices, skip i
        if (lane < K) {
            const int pos = (i < K + 1) ? i : (K + 1);
            idx = (lane < pos) ? lane : lane + 1;
            sel = true;
        }
    }

    unsigned word = 0;
    for (int c = 0; c < C; ++c) {
        const int ic = __shfl(idx, c);
        const int sc = __shfl((int)sel, c);
        if (sc && (ic >> 5) == lane) word |= 1u << (ic & 31);
    }
    return word;
}

// Mask build: one wave per row (grid-stride), writes 64 words (256 B) coalesced.
__global__ __launch_bounds__(256) void mask_kernel(
    const float* __restrict__ emb_s,
    const float* __restrict__ emb_t,
    const int* __restrict__ candidx,
    uint32_t* __restrict__ mask)
{
    const int lane = threadIdx.x & 63;
    const int wid = blockIdx.x * 4 + (threadIdx.x >> 6);
    const int nw = gridDim.x * 4;
    for (int row = wid; row < G * N; row += nw) {
        mask[(size_t)row * 64 + lane] = row_word(emb_s, emb_t, candidx, row, lane);
    }
}

// Memset-shaped writer: one wave per row. One coalesced dword load per row
// (lane l <- word l), then 8x {bpermute word + unpack + NT dwordx4 store},
// no branches, no cross-iteration dependencies.
__global__ __launch_bounds__(256) void stream_kernel(
    const uint32_t* __restrict__ mask,
    float* __restrict__ out)
{
    const int lane = threadIdx.x & 63;
    const int wid = blockIdx.x * 4 + (threadIdx.x >> 6);
    const int nw = gridDim.x * 4;
    for (int row = wid; row < G * N; row += nw) {
        const unsigned w = mask[(size_t)row * 64 + lane];
        floatx4* rowp = reinterpret_cast<floatx4*>(out + (size_t)row * N);
        #pragma unroll
        for (int c = 0; c < 8; ++c) {
            const unsigned ww = (unsigned)__shfl((int)w, c * 8 + (lane >> 3));
            const int b0 = (lane & 7) * 4;
            floatx4 v;
            v.x = (float)((ww >> (b0 + 0)) & 1u);
            v.y = (float)((ww >> (b0 + 1)) & 1u);
            v.z = (float)((ww >> (b0 + 2)) & 1u);
            v.w = (float)((ww >> (b0 + 3)) & 1u);
            __builtin_nontemporal_store(v, rowp + c * 64 + lane);
        }
    }
}

// Fallback (exact R3 structure, NT stores) if workspace too small for the mask.
__global__ __launch_bounds__(256) void fill_kernel(
    const float* __restrict__ emb_s,
    const float* __restrict__ emb_t,
    const int* __restrict__ candidx,
    float* __restrict__ out)
{
    const int lane = threadIdx.x & 63;
    const int wid = blockIdx.x * 4 + (threadIdx.x >> 6);
    const int nw = gridDim.x * 4;
    for (int row = wid; row < G * N; row += nw) {
        const unsigned word = row_word(emb_s, emb_t, candidx, row, lane);
        floatx4* rowp = reinterpret_cast<floatx4*>(out + (size_t)row * N);
        #pragma unroll
        for (int c = 0; c < 8; ++c) {
            const unsigned w = (unsigned)__shfl((int)word, c * 8 + (lane >> 3));
            const int b0 = (lane & 7) * 4;
            floatx4 v;
            v.x = (float)((w >> (b0 + 0)) & 1u);
            v.y = (float)((w >> (b0 + 1)) & 1u);
            v.z = (float)((w >> (b0 + 2)) & 1u);
            v.w = (float)((w >> (b0 + 3)) & 1u);
            __builtin_nontemporal_store(v, rowp + c * 64 + lane);
        }
    }
}

extern "C" void kernel_launch(void* const* d_in, const int* in_sizes, int n_in,
                              void* d_out, int out_size, void* d_ws, size_t ws_size,
                              hipStream_t stream) {
    const float* emb_s = (const float*)d_in[0];   // (G, N, 1) f32
    const float* emb_t = (const float*)d_in[1];   // (G, 1, N) f32

    int* candidx = (int*)d_ws;                    // [2*G][C] ints (2560 B)
    const size_t maskOff = 4096;
    const size_t needed = maskOff + (size_t)G * N * 64 * sizeof(uint32_t);  // ~8.4 MB

    topk_kernel<<<2 * G, 64, 0, stream>>>(emb_t, candidx);

    if (ws_size >= needed) {
        uint32_t* mask = (uint32_t*)((char*)d_ws + maskOff);
        mask_kernel<<<512, 256, 0, stream>>>(emb_s, emb_t, candidx, mask);
        stream_kernel<<<2048, 256, 0, stream>>>(mask, (float*)d_out);
    } else {
        fill_kernel<<<1024, 256, 0, stream>>>(emb_s, emb_t, candidx, (float*)d_out);
    }
}

// Round 6
// 148.997 us; speedup vs baseline: 1.0865x; 1.0865x over previous
//
#include <hip/hip_runtime.h>
#include <math.h>
#include <limits.h>
#include <stdint.h>

namespace {
constexpr int G = 16;    // num_graphs
constexpr int N = 2048;  // num_nodes
constexpr int K = 16;    // k_neighs
constexpr int C = 20;    // candidates per side (K + diag exclusion + tie slack)
typedef float floatx4 __attribute__((ext_vector_type(4)));
}

// 2*G blocks, 1 wave each. Block b: g = b>>1, side = b&1 (0 = largest t, 1 = smallest t).
// Register-resident; selection-without-removal via lexicographic cursor (pv,pi).
// Emits candidate indices in exact (value, then lower index) order — lax.top_k tie-break.
__global__ void topk_kernel(const float* __restrict__ emb_t,
                            int* __restrict__ candidx /* [2*G][C] */) {
    const int g = blockIdx.x >> 1;
    const int side = blockIdx.x & 1;
    const int lane = threadIdx.x;            // 64 = one wave
    const float sgn = side ? -1.f : 1.f;     // negate for min side -> always argmax

    float v[32];
    #pragma unroll
    for (int m = 0; m < 32; ++m) v[m] = sgn * emb_t[g * N + lane + 64 * m];

    float pv = INFINITY; int pi = -1;        // last selected (lexicographic cursor)
    for (int p = 0; p < C; ++p) {
        float bv = -INFINITY; int bi = INT_MAX;
        #pragma unroll
        for (int m = 0; m < 32; ++m) {
            const int idx = lane + 64 * m;
            const float x = v[m];
            // eligible iff strictly after (pv,pi) in (value desc, index asc) order
            const bool elig = (x < pv) || (x == pv && idx > pi);
            if (elig && (x > bv || (x == bv && idx < bi))) { bv = x; bi = idx; }
        }
        #pragma unroll
        for (int off = 32; off >= 1; off >>= 1) {
            const float ov = __shfl_xor(bv, off);
            const int   oi = __shfl_xor(bi, off);
            if (ov > bv || (ov == bv && oi < bi)) { bv = ov; bi = oi; }
        }
        if (lane == 0) candidx[blockIdx.x * C + p] = bi;
        pv = bv; pi = bi;
    }
}

// Pure dependency-free bulk zero: clone of the rocclr fillBuffer shape that
// sustains ~7 TB/s on this buffer. No loads, no DS, no branches in the body.
__global__ __launch_bounds__(256) void zero_kernel(floatx4* __restrict__ out) {
    const size_t total = (size_t)G * N * (N / 4);      // 16,777,216 float4s
    const size_t stride = (size_t)gridDim.x * 256;
    const floatx4 z = {0.f, 0.f, 0.f, 0.f};
    for (size_t q = (size_t)blockIdx.x * 256 + threadIdx.x; q < total; q += stride)
        out[q] = z;
}

// Sparse scatter: one wave per row (grid-stride). Rank the <=C candidates with
// exact lax.top_k tie semantics, then <=K lanes each store a single 1.0f.
__global__ __launch_bounds__(256) void scatter_kernel(
    const float* __restrict__ emb_s,
    const float* __restrict__ emb_t,
    const int* __restrict__ candidx,
    float* __restrict__ out)
{
    const int lane = threadIdx.x & 63;
    const int wid = blockIdx.x * 4 + (threadIdx.x >> 6);
    const int nw = gridDim.x * 4;

    for (int row = wid; row < G * N; row += nw) {
        const int g = row >> 11;             // N = 2048
        const int i = row & (N - 1);
        const float s = emb_s[row];

        int idx = INT_MAX;
        bool sel = false;
        if (s != 0.0f) {
            const int* list = candidx + (g * 2 + (s < 0.0f)) * C;
            float p = -INFINITY;
            if (lane < C) {
                idx = list[lane];
                p = s * emb_t[g * N + idx];          // same rounding as reference adj
                if (idx == i) { p = -INFINITY; idx = INT_MAX; }  // exclude diagonal
            }
            // exact top_k rank among candidates: (value desc, index asc)
            int rank = 0;
            for (int c = 0; c < C; ++c) {
                const float pc = __shfl(p, c);
                const int   ic = __shfl(idx, c);
                if (pc > p || (pc == p && ic < idx)) ++rank;
            }
            sel = (lane < C) && (rank < K) && (idx != INT_MAX);
        } else {
            // s == +/-0: all products are +/-0 (compare-equal) -> lowest K indices, skip i
            if (lane < K) {
                const int pos = (i < K + 1) ? i : (K + 1);
                idx = (lane < pos) ? lane : lane + 1;
                sel = true;
            }
        }

        if (sel) out[(size_t)row * N + idx] = 1.0f;
    }
}

extern "C" void kernel_launch(void* const* d_in, const int* in_sizes, int n_in,
                              void* d_out, int out_size, void* d_ws, size_t ws_size,
                              hipStream_t stream) {
    const float* emb_s = (const float*)d_in[0];   // (G, N, 1) f32
    const float* emb_t = (const float*)d_in[1];   // (G, 1, N) f32
    float* out = (float*)d_out;                   // (G, N, N) f32

    int* candidx = (int*)d_ws;                    // [2*G][C] ints (2560 B)

    topk_kernel<<<2 * G, 64, 0, stream>>>(emb_t, candidx);
    zero_kernel<<<2048, 256, 0, stream>>>((floatx4*)out);
    scatter_kernel<<<512, 256, 0, stream>>>(emb_s, emb_t, candidx, out);
}

// Round 7
// 136.974 us; speedup vs baseline: 1.1819x; 1.0878x over previous
//
#include <hip/hip_runtime.h>
#include <math.h>
#include <limits.h>
#include <stdint.h>

namespace {
constexpr int G = 16;    // num_graphs
constexpr int N = 2048;  // num_nodes
constexpr int K = 16;    // k_neighs
constexpr int C = 20;    // candidates per side (K + diag exclusion + tie slack)
typedef float floatx4 __attribute__((ext_vector_type(4)));
}

// 2*G blocks, 1 wave each. Block b: g = b>>1, side = b&1 (0 = largest t, 1 = smallest t).
// Register-resident; selection-without-removal via lexicographic cursor (pv,pi).
// Emits candidate indices in exact (value, then lower index) order — lax.top_k tie-break.
__global__ void topk_kernel(const float* __restrict__ emb_t,
                            int* __restrict__ candidx /* [2*G][C] */) {
    const int g = blockIdx.x >> 1;
    const int side = blockIdx.x & 1;
    const int lane = threadIdx.x;            // 64 = one wave
    const float sgn = side ? -1.f : 1.f;     // negate for min side -> always argmax

    float v[32];
    #pragma unroll
    for (int m = 0; m < 32; ++m) v[m] = sgn * emb_t[g * N + lane + 64 * m];

    float pv = INFINITY; int pi = -1;        // last selected (lexicographic cursor)
    for (int p = 0; p < C; ++p) {
        float bv = -INFINITY; int bi = INT_MAX;
        #pragma unroll
        for (int m = 0; m < 32; ++m) {
            const int idx = lane + 64 * m;
            const float x = v[m];
            const bool elig = (x < pv) || (x == pv && idx > pi);
            if (elig && (x > bv || (x == bv && idx < bi))) { bv = x; bi = idx; }
        }
        #pragma unroll
        for (int off = 32; off >= 1; off >>= 1) {
            const float ov = __shfl_xor(bv, off);
            const int   oi = __shfl_xor(bi, off);
            if (ov > bv || (ov == bv && oi < bi)) { bv = ov; bi = oi; }
        }
        if (lane == 0) candidx[blockIdx.x * C + p] = bi;
        pv = bv; pi = bi;
    }
}

// Flag rows whose exact mask may differ from the per-(g,side) base mask.
// IEEE multiply by fixed s is monotone in t, so the top-16 SET equals the base
// top-16 unless: s==0, or i is inside the base top-16 (diagonal exclusion), or
// the products tie exactly at the 16/17 boundary (set membership ambiguous).
__global__ __launch_bounds__(256) void det_kernel(
    const float* __restrict__ emb_s,
    const float* __restrict__ emb_t,
    const int* __restrict__ candidx,
    unsigned char* __restrict__ flags)
{
    const int lane = threadIdx.x & 63;
    const int wid = blockIdx.x * 4 + (threadIdx.x >> 6);
    const int nw = gridDim.x * 4;
    for (int row = wid; row < G * N; row += nw) {
        const int g = row >> 11;
        const int i = row & (N - 1);
        const float s = emb_s[row];
        const int side = (__float_as_int(s) < 0) ? 1 : 0;
        const int* list = candidx + (2 * g + side) * C;
        float p = 0.f; int idx = -1;
        if (lane < C) { idx = list[lane]; p = s * emb_t[g * N + idx]; }
        const float p15 = __shfl(p, 15);
        const float p16 = __shfl(p, 16);
        const unsigned long long inTop = __ballot((lane < K) && (idx == i));
        const bool special = (s == 0.0f) || (inTop != 0ull) || (p15 == p16);
        if (lane == 0) flags[row] = special ? 1 : 0;
    }
}

// Bulk writer: per (g,side) the row image is FIXED. Build both images once into
// 16 payload float4 registers, then per row: one scalar sign test + 8 NT stores.
// No per-row vector logic at all — memset-shaped store stream from registers.
__global__ __launch_bounds__(256) void fill_kernel(
    const float* __restrict__ emb_s,
    const int* __restrict__ candidx,
    float* __restrict__ out)
{
    const int lane = threadIdx.x & 63;
    const int wave = threadIdx.x >> 6;
    const int rowbase = blockIdx.x * 64 + wave * 16;   // 16 rows per wave, same g
    const int g = rowbase >> 11;

    // Base mask words (lane l holds word l): top-16 of each side.
    unsigned wpos = 0, wneg = 0;
    #pragma unroll
    for (int c = 0; c < K; ++c) {
        const int ip = candidx[(2 * g + 0) * C + c];
        const int in_ = candidx[(2 * g + 1) * C + c];
        if ((ip >> 5) == lane) wpos |= 1u << (ip & 31);
        if ((in_ >> 5) == lane) wneg |= 1u << (in_ & 31);
    }
    // Payload registers: chunk c, this lane covers columns c*256 + 4*lane + {0..3}.
    floatx4 pos[8], neg[8];
    #pragma unroll
    for (int c = 0; c < 8; ++c) {
        const unsigned wp = (unsigned)__shfl((int)wpos, c * 8 + (lane >> 3));
        const unsigned wn = (unsigned)__shfl((int)wneg, c * 8 + (lane >> 3));
        const int b0 = (lane & 7) * 4;
        pos[c].x = (float)((wp >> (b0 + 0)) & 1u);
        pos[c].y = (float)((wp >> (b0 + 1)) & 1u);
        pos[c].z = (float)((wp >> (b0 + 2)) & 1u);
        pos[c].w = (float)((wp >> (b0 + 3)) & 1u);
        neg[c].x = (float)((wn >> (b0 + 0)) & 1u);
        neg[c].y = (float)((wn >> (b0 + 1)) & 1u);
        neg[c].z = (float)((wn >> (b0 + 2)) & 1u);
        neg[c].w = (float)((wn >> (b0 + 3)) & 1u);
    }

    for (int r = 0; r < 16; ++r) {
        const int row = rowbase + r;
        const int su = __builtin_amdgcn_readfirstlane(__float_as_int(emb_s[row]));
        floatx4* rp = reinterpret_cast<floatx4*>(out + (size_t)row * N);
        if (su < 0) {
            #pragma unroll
            for (int c = 0; c < 8; ++c)
                __builtin_nontemporal_store(neg[c], rp + c * 64 + lane);
        } else {
            #pragma unroll
            for (int c = 0; c < 8; ++c)
                __builtin_nontemporal_store(pos[c], rp + c * 64 + lane);
        }
    }
}

// Exact per-row mask (proven R6 logic) — used only for flagged rows.
__device__ __forceinline__ unsigned row_word(const float* __restrict__ emb_s,
                                             const float* __restrict__ emb_t,
                                             const int* __restrict__ candidx,
                                             int row, int lane) {
    const int g = row >> 11;
    const int i = row & (N - 1);
    const float s = emb_s[row];

    int idx = INT_MAX;
    bool sel = false;
    if (s != 0.0f) {
        const int* list = candidx + (g * 2 + (s < 0.0f)) * C;
        float p = -INFINITY;
        if (lane < C) {
            idx = list[lane];
            p = s * emb_t[g * N + idx];
            if (idx == i) { p = -INFINITY; idx = INT_MAX; }
        }
        int rank = 0;
        for (int c = 0; c < C; ++c) {
            const float pc = __shfl(p, c);
            const int   ic = __shfl(idx, c);
            if (pc > p || (pc == p && ic < idx)) ++rank;
        }
        sel = (lane < C) && (rank < K) && (idx != INT_MAX);
    } else {
        if (lane < K) {
            const int pos = (i < K + 1) ? i : (K + 1);
            idx = (lane < pos) ? lane : lane + 1;
            sel = true;
        }
    }

    unsigned word = 0;
    for (int c = 0; c < C; ++c) {
        const int ic = __shfl(idx, c);
        const int sc = __shfl((int)sel, c);
        if (sc && (ic >> 5) == lane) word |= 1u << (ic & 31);
    }
    return word;
}

// Rewrite flagged rows exactly. One wave scans 64 flags; expected ~0 set.
__global__ __launch_bounds__(256) void patch_kernel(
    const float* __restrict__ emb_s,
    const float* __restrict__ emb_t,
    const int* __restrict__ candidx,
    const unsigned char* __restrict__ flags,
    float* __restrict__ out)
{
    const int lane = threadIdx.x & 63;
    const int wid = blockIdx.x * 4 + (threadIdx.x >> 6);
    const int base = wid * 64;
    if (base >= G * N) return;

    unsigned long long m = __ballot(flags[base + lane] != 0);
    while (m != 0ull) {
        const int b = __builtin_ctzll(m); m &= m - 1;
        const int row = base + b;
        const unsigned word = row_word(emb_s, emb_t, candidx, row, lane);
        floatx4* rp = reinterpret_cast<floatx4*>(out + (size_t)row * N);
        #pragma unroll
        for (int c = 0; c < 8; ++c) {
            const unsigned w = (unsigned)__shfl((int)word, c * 8 + (lane >> 3));
            const int b0 = (lane & 7) * 4;
            floatx4 v;
            v.x = (float)((w >> (b0 + 0)) & 1u);
            v.y = (float)((w >> (b0 + 1)) & 1u);
            v.z = (float)((w >> (b0 + 2)) & 1u);
            v.w = (float)((w >> (b0 + 3)) & 1u);
            *(rp + c * 64 + lane) = v;
        }
    }
}

// Fallback (R6 chain) if workspace is unexpectedly tiny.
__global__ __launch_bounds__(256) void zero_kernel(floatx4* __restrict__ out) {
    const size_t total = (size_t)G * N * (N / 4);
    const size_t stride = (size_t)gridDim.x * 256;
    const floatx4 z = {0.f, 0.f, 0.f, 0.f};
    for (size_t q = (size_t)blockIdx.x * 256 + threadIdx.x; q < total; q += stride)
        out[q] = z;
}
__global__ __launch_bounds__(256) void scatter_kernel(
    const float* __restrict__ emb_s,
    const float* __restrict__ emb_t,
    const int* __restrict__ candidx,
    float* __restrict__ out)
{
    const int lane = threadIdx.x & 63;
    const int wid = blockIdx.x * 4 + (threadIdx.x >> 6);
    const int nw = gridDim.x * 4;
    for (int row = wid; row < G * N; row += nw) {
        const int g = row >> 11;
        const int i = row & (N - 1);
        const float s = emb_s[row];
        int idx = INT_MAX; bool sel = false;
        if (s != 0.0f) {
            const int* list = candidx + (g * 2 + (s < 0.0f)) * C;
            float p = -INFINITY;
            if (lane < C) {
                idx = list[lane];
                p = s * emb_t[g * N + idx];
                if (idx == i) { p = -INFINITY; idx = INT_MAX; }
            }
            int rank = 0;
            for (int c = 0; c < C; ++c) {
                const float pc = __shfl(p, c);
                const int   ic = __shfl(idx, c);
                if (pc > p || (pc == p && ic < idx)) ++rank;
            }
            sel = (lane < C) && (rank < K) && (idx != INT_MAX);
        } else if (lane < K) {
            const int pos = (i < K + 1) ? i : (K + 1);
            idx = (lane < pos) ? lane : lane + 1;
            sel = true;
        }
        if (sel) out[(size_t)row * N + idx] = 1.0f;
    }
}

extern "C" void kernel_launch(void* const* d_in, const int* in_sizes, int n_in,
                              void* d_out, int out_size, void* d_ws, size_t ws_size,
                              hipStream_t stream) {
    const float* emb_s = (const float*)d_in[0];   // (G, N, 1) f32
    const float* emb_t = (const float*)d_in[1];   // (G, 1, N) f32
    float* out = (float*)d_out;                   // (G, N, N) f32

    int* candidx = (int*)d_ws;                            // 2560 B
    unsigned char* flags = (unsigned char*)d_ws + 4096;   // 32768 B
    const size_t needed = 4096 + (size_t)G * N;

    topk_kernel<<<2 * G, 64, 0, stream>>>(emb_t, candidx);

    if (ws_size >= needed) {
        det_kernel<<<512, 256, 0, stream>>>(emb_s, emb_t, candidx, flags);
        fill_kernel<<<G * N / 64, 256, 0, stream>>>(emb_s, candidx, out);
        patch_kernel<<<G * N / 64 / 4, 256, 0, stream>>>(emb_s, emb_t, candidx, flags, out);
    } else {
        zero_kernel<<<2048, 256, 0, stream>>>((floatx4*)out);
        scatter_kernel<<<512, 256, 0, stream>>>(emb_s, emb_t, candidx, out);
    }
}

// Round 8
// 121.519 us; speedup vs baseline: 1.3322x; 1.1272x over previous
//
#include <hip/hip_runtime.h>
#include <math.h>
#include <limits.h>
#include <stdint.h>

namespace {
constexpr int G = 16;    // num_graphs
constexpr int N = 2048;  // num_nodes
constexpr int K = 16;    // k_neighs
constexpr int C = 20;    // candidates per side (K + diag exclusion + tie slack)
typedef float floatx4 __attribute__((ext_vector_type(4)));
}

// 2*G blocks, 1 wave each. Block b: g=b>>1, side=b&1 (0: largest t, 1: smallest t).
// Register-resident selection via lexicographic cursor. Also emits the 64-word
// base top-16 mask and the (t_c15, t_c16) boundary pair for the tie test.
__global__ void topk_kernel(const float* __restrict__ emb_t,
                            int* __restrict__ candidx /* [2G][C] */,
                            float* __restrict__ boundary /* [2G][2] */,
                            unsigned* __restrict__ basemask /* [2G][64] */) {
    const int g = blockIdx.x >> 1;
    const int side = blockIdx.x & 1;
    const int lane = threadIdx.x;            // 64 = one wave
    const float sgn = side ? -1.f : 1.f;     // negate for min side -> always argmax

    float v[32];
    #pragma unroll
    for (int m = 0; m < 32; ++m) v[m] = sgn * emb_t[g * N + lane + 64 * m];

    float pv = INFINITY; int pi = -1;        // lexicographic cursor
    unsigned mw = 0;                          // this lane's base-mask word
    float b15 = 0.f, b16 = 0.f;
    for (int p = 0; p < C; ++p) {
        float bv = -INFINITY; int bi = INT_MAX;
        #pragma unroll
        for (int m = 0; m < 32; ++m) {
            const int idx = lane + 64 * m;
            const float x = v[m];
            const bool elig = (x < pv) || (x == pv && idx > pi);
            if (elig && (x > bv || (x == bv && idx < bi))) { bv = x; bi = idx; }
        }
        #pragma unroll
        for (int off = 32; off >= 1; off >>= 1) {
            const float ov = __shfl_xor(bv, off);
            const int   oi = __shfl_xor(bi, off);
            if (ov > bv || (ov == bv && oi < bi)) { bv = ov; bi = oi; }
        }
        if (lane == 0) candidx[blockIdx.x * C + p] = bi;
        if (p < K && (bi >> 5) == lane) mw |= 1u << (bi & 31);
        if (p == 15) b15 = bv;
        if (p == 16) b16 = bv;
        pv = bv; pi = bi;
    }
    basemask[blockIdx.x * 64 + lane] = mw;
    if (lane == 0) {
        boundary[blockIdx.x * 2 + 0] = sgn * b15;   // original t values
        boundary[blockIdx.x * 2 + 1] = sgn * b16;
    }
}

// One lane per row: compress sign + "may deviate from base mask" into bitmasks.
// Deviation superset: s==0, or i inside base top-16, or exact product tie at the
// 16/17 boundary (IEEE mul by fixed s is monotone in t otherwise).
__global__ __launch_bounds__(256) void prep_kernel(
    const float* __restrict__ emb_s,
    const float* __restrict__ boundary,
    const unsigned* __restrict__ basemask,
    unsigned* __restrict__ signw /* [G*N/32] */,
    unsigned* __restrict__ specialw /* [G*N/32] */) {
    const int lane = threadIdx.x & 63;
    const int wid = blockIdx.x * 4 + (threadIdx.x >> 6);   // 0..511, 64 rows each
    const int row = wid * 64 + lane;
    const int g = row >> 11;
    const int i = row & (N - 1);
    const float s = emb_s[row];
    const bool sneg = __float_as_int(s) < 0;
    const int tb = 2 * g + (sneg ? 1 : 0);
    const unsigned w = basemask[tb * 64 + (i >> 5)];
    const bool inTop = (w >> (i & 31)) & 1u;
    const float a = boundary[tb * 2 + 0];
    const float b = boundary[tb * 2 + 1];
    const bool special = (s == 0.0f) || inTop || (s * a == s * b);
    const unsigned long long sm = __ballot(sneg);
    const unsigned long long pm = __ballot(special);
    if (lane == 0) {
        signw[wid * 2 + 0] = (unsigned)sm;
        signw[wid * 2 + 1] = (unsigned)(sm >> 32);
        specialw[wid * 2 + 0] = (unsigned)pm;
        specialw[wid * 2 + 1] = (unsigned)(pm >> 32);
    }
}

// Exact per-row mask (proven logic) — only for flagged rows.
__device__ __forceinline__ unsigned row_word(const float* __restrict__ emb_s,
                                             const float* __restrict__ emb_t,
                                             const int* __restrict__ candidx,
                                             int row, int lane) {
    const int g = row >> 11;
    const int i = row & (N - 1);
    const float s = emb_s[row];

    int idx = INT_MAX;
    bool sel = false;
    if (s != 0.0f) {
        const int* list = candidx + (g * 2 + (s < 0.0f)) * C;
        float p = -INFINITY;
        if (lane < C) {
            idx = list[lane];
            p = s * emb_t[g * N + idx];
            if (idx == i) { p = -INFINITY; idx = INT_MAX; }
        }
        int rank = 0;
        for (int c = 0; c < C; ++c) {
            const float pc = __shfl(p, c);
            const int   ic = __shfl(idx, c);
            if (pc > p || (pc == p && ic < idx)) ++rank;
        }
        sel = (lane < C) && (rank < K) && (idx != INT_MAX);
    } else {
        if (lane < K) {
            const int pos = (i < K + 1) ? i : (K + 1);
            idx = (lane < pos) ? lane : lane + 1;
            sel = true;
        }
    }

    unsigned word = 0;
    for (int c = 0; c < C; ++c) {
        const int ic = __shfl(idx, c);
        const int sc = __shfl((int)sel, c);
        if (sc && (ic >> 5) == lane) word |= 1u << (ic & 31);
    }
    return word;
}

// Bulk writer: per wave, build both row images in registers once, then
// 16 rows x 8 NT dwordx4 stores with only SGPR bit tests between bursts.
// ZERO loads / shuffles / VMEM dependencies inside the store loop.
__global__ __launch_bounds__(256) void fill_kernel(
    const float* __restrict__ emb_s,
    const float* __restrict__ emb_t,
    const int* __restrict__ candidx,
    const unsigned* __restrict__ basemask,
    const unsigned* __restrict__ signw,
    const unsigned* __restrict__ specialw,
    float* __restrict__ out)
{
    const int lane = threadIdx.x & 63;
    const int wave = threadIdx.x >> 6;
    const int rowbase = blockIdx.x * 64 + wave * 16;   // 16 consecutive rows
    const int g = rowbase >> 11;

    // Wave-uniform per-16-row state (one word covers 32 rows).
    const unsigned sw = __builtin_amdgcn_readfirstlane(signw[rowbase >> 5]) >> (rowbase & 31);
    const unsigned pw = __builtin_amdgcn_readfirstlane(specialw[rowbase >> 5]) >> (rowbase & 31);

    // Build both row images (lane l holds mask word l -> shuffle to payload).
    const unsigned wpos = basemask[(2 * g + 0) * 64 + lane];
    const unsigned wneg = basemask[(2 * g + 1) * 64 + lane];
    floatx4 pos[8], neg[8];
    #pragma unroll
    for (int c = 0; c < 8; ++c) {
        const unsigned wp = (unsigned)__shfl((int)wpos, c * 8 + (lane >> 3));
        const unsigned wn = (unsigned)__shfl((int)wneg, c * 8 + (lane >> 3));
        const int b0 = (lane & 7) * 4;
        pos[c].x = (float)((wp >> (b0 + 0)) & 1u);
        pos[c].y = (float)((wp >> (b0 + 1)) & 1u);
        pos[c].z = (float)((wp >> (b0 + 2)) & 1u);
        pos[c].w = (float)((wp >> (b0 + 3)) & 1u);
        neg[c].x = (float)((wn >> (b0 + 0)) & 1u);
        neg[c].y = (float)((wn >> (b0 + 1)) & 1u);
        neg[c].z = (float)((wn >> (b0 + 2)) & 1u);
        neg[c].w = (float)((wn >> (b0 + 3)) & 1u);
    }

    #pragma unroll 1
    for (int r = 0; r < 16; ++r) {
        const int row = rowbase + r;
        floatx4* rp = reinterpret_cast<floatx4*>(out + (size_t)row * N);
        if ((pw >> r) & 1u) {
            // rare exact path (expected never): recompute row precisely
            const unsigned word = row_word(emb_s, emb_t, candidx, row, lane);
            #pragma unroll
            for (int c = 0; c < 8; ++c) {
                const unsigned w = (unsigned)__shfl((int)word, c * 8 + (lane >> 3));
                const int b0 = (lane & 7) * 4;
                floatx4 v;
                v.x = (float)((w >> (b0 + 0)) & 1u);
                v.y = (float)((w >> (b0 + 1)) & 1u);
                v.z = (float)((w >> (b0 + 2)) & 1u);
                v.w = (float)((w >> (b0 + 3)) & 1u);
                *(rp + c * 64 + lane) = v;
            }
        } else if ((sw >> r) & 1u) {
            #pragma unroll
            for (int c = 0; c < 8; ++c)
                __builtin_nontemporal_store(neg[c], rp + c * 64 + lane);
        } else {
            #pragma unroll
            for (int c = 0; c < 8; ++c)
                __builtin_nontemporal_store(pos[c], rp + c * 64 + lane);
        }
    }
}

// Fallback chain (proven) if workspace is unexpectedly tiny.
__global__ __launch_bounds__(256) void zero_kernel(floatx4* __restrict__ out) {
    const size_t total = (size_t)G * N * (N / 4);
    const size_t stride = (size_t)gridDim.x * 256;
    const floatx4 z = {0.f, 0.f, 0.f, 0.f};
    for (size_t q = (size_t)blockIdx.x * 256 + threadIdx.x; q < total; q += stride)
        out[q] = z;
}
__global__ __launch_bounds__(256) void scatter_kernel(
    const float* __restrict__ emb_s,
    const float* __restrict__ emb_t,
    const int* __restrict__ candidx,
    float* __restrict__ out)
{
    const int lane = threadIdx.x & 63;
    const int wid = blockIdx.x * 4 + (threadIdx.x >> 6);
    const int nw = gridDim.x * 4;
    for (int row = wid; row < G * N; row += nw) {
        const unsigned word = row_word(emb_s, emb_t, candidx, row, lane);
        // scatter set bits
        unsigned w = word;
        while (w) {
            const int b = __builtin_ctz(w); w &= w - 1;
            out[(size_t)row * N + lane * 32 + b] = 1.0f;
        }
    }
}

extern "C" void kernel_launch(void* const* d_in, const int* in_sizes, int n_in,
                              void* d_out, int out_size, void* d_ws, size_t ws_size,
                              hipStream_t stream) {
    const float* emb_s = (const float*)d_in[0];   // (G, N, 1) f32
    const float* emb_t = (const float*)d_in[1];   // (G, 1, N) f32
    float* out = (float*)d_out;                   // (G, N, N) f32

    int* candidx        = (int*)d_ws;                          // 2560 B
    float* boundary     = (float*)((char*)d_ws + 4096);        // 256 B
    unsigned* basemask  = (unsigned*)((char*)d_ws + 8192);     // 8192 B
    unsigned* signw     = (unsigned*)((char*)d_ws + 16384);    // 4096 B
    unsigned* specialw  = (unsigned*)((char*)d_ws + 20480);    // 4096 B
    const size_t needed = 24576 + 4096;

    topk_kernel<<<2 * G, 64, 0, stream>>>(emb_t, candidx, boundary, basemask);

    if (ws_size >= needed) {
        prep_kernel<<<128, 256, 0, stream>>>(emb_s, boundary, basemask, signw, specialw);
        fill_kernel<<<G * N / 64, 256, 0, stream>>>(emb_s, emb_t, candidx, basemask,
                                                    signw, specialw, out);
    } else {
        zero_kernel<<<2048, 256, 0, stream>>>((floatx4*)out);
        scatter_kernel<<<512, 256, 0, stream>>>(emb_s, emb_t, candidx, out);
    }
}

// Round 9
// 106.978 us; speedup vs baseline: 1.5133x; 1.1359x over previous
//
#include <hip/hip_runtime.h>
#include <math.h>
#include <limits.h>
#include <stdint.h>

namespace {
constexpr int G = 16;    // num_graphs
constexpr int N = 2048;  // num_nodes
constexpr int K = 16;    // k_neighs
constexpr int C = 20;    // candidates per side (K + diag exclusion + tie slack)
typedef float floatx4 __attribute__((ext_vector_type(4)));
}

// 2*G blocks, 1 wave each. Block b: g=b>>1, side=b&1 (0: largest t, 1: smallest t).
// Register-resident selection via lexicographic cursor. Also emits the 64-word
// base top-16 mask and the (t_c15, t_c16) boundary pair for the tie test.
__global__ void topk_kernel(const float* __restrict__ emb_t,
                            int* __restrict__ candidx /* [2G][C] */,
                            float* __restrict__ boundary /* [2G][2] */,
                            unsigned* __restrict__ basemask /* [2G][64] */) {
    const int g = blockIdx.x >> 1;
    const int side = blockIdx.x & 1;
    const int lane = threadIdx.x;            // 64 = one wave
    const float sgn = side ? -1.f : 1.f;     // negate for min side -> always argmax

    float v[32];
    #pragma unroll
    for (int m = 0; m < 32; ++m) v[m] = sgn * emb_t[g * N + lane + 64 * m];

    float pv = INFINITY; int pi = -1;        // lexicographic cursor
    unsigned mw = 0;                          // this lane's base-mask word
    float b15 = 0.f, b16 = 0.f;
    for (int p = 0; p < C; ++p) {
        float bv = -INFINITY; int bi = INT_MAX;
        #pragma unroll
        for (int m = 0; m < 32; ++m) {
            const int idx = lane + 64 * m;
            const float x = v[m];
            const bool elig = (x < pv) || (x == pv && idx > pi);
            if (elig && (x > bv || (x == bv && idx < bi))) { bv = x; bi = idx; }
        }
        #pragma unroll
        for (int off = 32; off >= 1; off >>= 1) {
            const float ov = __shfl_xor(bv, off);
            const int   oi = __shfl_xor(bi, off);
            if (ov > bv || (ov == bv && oi < bi)) { bv = ov; bi = oi; }
        }
        if (lane == 0) candidx[blockIdx.x * C + p] = bi;
        if (p < K && (bi >> 5) == lane) mw |= 1u << (bi & 31);
        if (p == 15) b15 = bv;
        if (p == 16) b16 = bv;
        pv = bv; pi = bi;
    }
    basemask[blockIdx.x * 64 + lane] = mw;
    if (lane == 0) {
        boundary[blockIdx.x * 2 + 0] = sgn * b15;   // original t values
        boundary[blockIdx.x * 2 + 1] = sgn * b16;
    }
}

// One lane per row: compress sign + "may deviate from base mask" into bitmasks.
// Deviation superset: s==0, or i inside base top-16, or exact product tie at the
// 16/17 boundary (IEEE mul by fixed s is monotone in t otherwise).
__global__ __launch_bounds__(256) void prep_kernel(
    const float* __restrict__ emb_s,
    const float* __restrict__ boundary,
    const unsigned* __restrict__ basemask,
    unsigned* __restrict__ signw /* [G*N/32] */,
    unsigned* __restrict__ specialw /* [G*N/32] */) {
    const int lane = threadIdx.x & 63;
    const int wid = blockIdx.x * 4 + (threadIdx.x >> 6);   // 0..511, 64 rows each
    const int row = wid * 64 + lane;
    const int g = row >> 11;
    const int i = row & (N - 1);
    const float s = emb_s[row];
    const bool sneg = __float_as_int(s) < 0;
    const int tb = 2 * g + (sneg ? 1 : 0);
    const unsigned w = basemask[tb * 64 + (i >> 5)];
    const bool inTop = (w >> (i & 31)) & 1u;
    const float a = boundary[tb * 2 + 0];
    const float b = boundary[tb * 2 + 1];
    const bool special = (s == 0.0f) || inTop || (s * a == s * b);
    const unsigned long long sm = __ballot(sneg);
    const unsigned long long pm = __ballot(special);
    if (lane == 0) {
        signw[wid * 2 + 0] = (unsigned)sm;
        signw[wid * 2 + 1] = (unsigned)(sm >> 32);
        specialw[wid * 2 + 0] = (unsigned)pm;
        specialw[wid * 2 + 1] = (unsigned)(pm >> 32);
    }
}

// Exact per-row mask (proven logic) — only for flagged rows.
__device__ __forceinline__ unsigned row_word(const float* __restrict__ emb_s,
                                             const float* __restrict__ emb_t,
                                             const int* __restrict__ candidx,
                                             int row, int lane) {
    const int g = row >> 11;
    const int i = row & (N - 1);
    const float s = emb_s[row];

    int idx = INT_MAX;
    bool sel = false;
    if (s != 0.0f) {
        const int* list = candidx + (g * 2 + (s < 0.0f)) * C;
        float p = -INFINITY;
        if (lane < C) {
            idx = list[lane];
            p = s * emb_t[g * N + idx];
            if (idx == i) { p = -INFINITY; idx = INT_MAX; }
        }
        int rank = 0;
        for (int c = 0; c < C; ++c) {
            const float pc = __shfl(p, c);
            const int   ic = __shfl(idx, c);
            if (pc > p || (pc == p && ic < idx)) ++rank;
        }
        sel = (lane < C) && (rank < K) && (idx != INT_MAX);
    } else {
        if (lane < K) {
            const int pos = (i < K + 1) ? i : (K + 1);
            idx = (lane < pos) ? lane : lane + 1;
            sel = true;
        }
    }

    unsigned word = 0;
    for (int c = 0; c < C; ++c) {
        const int ic = __shfl(idx, c);
        const int sc = __shfl((int)sel, c);
        if (sc && (ic >> 5) == lane) word |= 1u << (ic & 31);
    }
    return word;
}

// Bulk writer: per wave, build both row images in registers once, then
// 16 rows x 8 REGULAR dwordx4 stores with only SGPR bit tests between bursts.
// (A/B vs R8: nontemporal -> regular is the ONLY change in this kernel.)
__global__ __launch_bounds__(256) void fill_kernel(
    const float* __restrict__ emb_s,
    const float* __restrict__ emb_t,
    const int* __restrict__ candidx,
    const unsigned* __restrict__ basemask,
    const unsigned* __restrict__ signw,
    const unsigned* __restrict__ specialw,
    float* __restrict__ out)
{
    const int lane = threadIdx.x & 63;
    const int wave = threadIdx.x >> 6;
    const int rowbase = blockIdx.x * 64 + wave * 16;   // 16 consecutive rows
    const int g = rowbase >> 11;

    // Wave-uniform per-16-row state (one word covers 32 rows).
    const unsigned sw = __builtin_amdgcn_readfirstlane(signw[rowbase >> 5]) >> (rowbase & 31);
    const unsigned pw = __builtin_amdgcn_readfirstlane(specialw[rowbase >> 5]) >> (rowbase & 31);

    // Build both row images (lane l holds mask word l -> shuffle to payload).
    const unsigned wpos = basemask[(2 * g + 0) * 64 + lane];
    const unsigned wneg = basemask[(2 * g + 1) * 64 + lane];
    floatx4 pos[8], neg[8];
    #pragma unroll
    for (int c = 0; c < 8; ++c) {
        const unsigned wp = (unsigned)__shfl((int)wpos, c * 8 + (lane >> 3));
        const unsigned wn = (unsigned)__shfl((int)wneg, c * 8 + (lane >> 3));
        const int b0 = (lane & 7) * 4;
        pos[c].x = (float)((wp >> (b0 + 0)) & 1u);
        pos[c].y = (float)((wp >> (b0 + 1)) & 1u);
        pos[c].z = (float)((wp >> (b0 + 2)) & 1u);
        pos[c].w = (float)((wp >> (b0 + 3)) & 1u);
        neg[c].x = (float)((wn >> (b0 + 0)) & 1u);
        neg[c].y = (float)((wn >> (b0 + 1)) & 1u);
        neg[c].z = (float)((wn >> (b0 + 2)) & 1u);
        neg[c].w = (float)((wn >> (b0 + 3)) & 1u);
    }

    #pragma unroll 1
    for (int r = 0; r < 16; ++r) {
        const int row = rowbase + r;
        floatx4* rp = reinterpret_cast<floatx4*>(out + (size_t)row * N);
        if ((pw >> r) & 1u) {
            // rare exact path (expected never): recompute row precisely
            const unsigned word = row_word(emb_s, emb_t, candidx, row, lane);
            #pragma unroll
            for (int c = 0; c < 8; ++c) {
                const unsigned w = (unsigned)__shfl((int)word, c * 8 + (lane >> 3));
                const int b0 = (lane & 7) * 4;
                floatx4 v;
                v.x = (float)((w >> (b0 + 0)) & 1u);
                v.y = (float)((w >> (b0 + 1)) & 1u);
                v.z = (float)((w >> (b0 + 2)) & 1u);
                v.w = (float)((w >> (b0 + 3)) & 1u);
                *(rp + c * 64 + lane) = v;
            }
        } else if ((sw >> r) & 1u) {
            #pragma unroll
            for (int c = 0; c < 8; ++c)
                *(rp + c * 64 + lane) = neg[c];
        } else {
            #pragma unroll
            for (int c = 0; c < 8; ++c)
                *(rp + c * 64 + lane) = pos[c];
        }
    }
}

// Fallback chain (proven) if workspace is unexpectedly tiny.
__global__ __launch_bounds__(256) void zero_kernel(floatx4* __restrict__ out) {
    const size_t total = (size_t)G * N * (N / 4);
    const size_t stride = (size_t)gridDim.x * 256;
    const floatx4 z = {0.f, 0.f, 0.f, 0.f};
    for (size_t q = (size_t)blockIdx.x * 256 + threadIdx.x; q < total; q += stride)
        out[q] = z;
}
__global__ __launch_bounds__(256) void scatter_kernel(
    const float* __restrict__ emb_s,
    const float* __restrict__ emb_t,
    const int* __restrict__ candidx,
    float* __restrict__ out)
{
    const int lane = threadIdx.x & 63;
    const int wid = blockIdx.x * 4 + (threadIdx.x >> 6);
    const int nw = gridDim.x * 4;
    for (int row = wid; row < G * N; row += nw) {
        const unsigned word = row_word(emb_s, emb_t, candidx, row, lane);
        unsigned w = word;
        while (w) {
            const int b = __builtin_ctz(w); w &= w - 1;
            out[(size_t)row * N + lane * 32 + b] = 1.0f;
        }
    }
}

extern "C" void kernel_launch(void* const* d_in, const int* in_sizes, int n_in,
                              void* d_out, int out_size, void* d_ws, size_t ws_size,
                              hipStream_t stream) {
    const float* emb_s = (const float*)d_in[0];   // (G, N, 1) f32
    const float* emb_t = (const float*)d_in[1];   // (G, 1, N) f32
    float* out = (float*)d_out;                   // (G, N, N) f32

    int* candidx        = (int*)d_ws;                          // 2560 B
    float* boundary     = (float*)((char*)d_ws + 4096);        // 256 B
    unsigned* basemask  = (unsigned*)((char*)d_ws + 8192);     // 8192 B
    unsigned* signw     = (unsigned*)((char*)d_ws + 16384);    // 4096 B
    unsigned* specialw  = (unsigned*)((char*)d_ws + 20480);    // 4096 B
    const size_t needed = 24576 + 4096;

    topk_kernel<<<2 * G, 64, 0, stream>>>(emb_t, candidx, boundary, basemask);

    if (ws_size >= needed) {
        prep_kernel<<<128, 256, 0, stream>>>(emb_s, boundary, basemask, signw, specialw);
        fill_kernel<<<G * N / 64, 256, 0, stream>>>(emb_s, emb_t, candidx, basemask,
                                                    signw, specialw, out);
    } else {
        zero_kernel<<<2048, 256, 0, stream>>>((floatx4*)out);
        scatter_kernel<<<512, 256, 0, stream>>>(emb_s, emb_t, candidx, out);
    }
}